// Round 10
// baseline (240.549 us; speedup 1.0000x reference)
//
#include <hip/hip_runtime.h>

#define Bb 64
#define Nn 1152
#define Oo 32
#define DOv 16
#define DIv 8
#define BPB 16   // b's per block
#define NG 4     // b's per thread

// async global->LDS, 16B per lane
__device__ __forceinline__ void gload_lds16(const void* g, void* l) {
    __builtin_amdgcn_global_load_lds(
        (const __attribute__((address_space(1))) unsigned*)g,
        (__attribute__((address_space(3))) unsigned*)l, 16, 0, 0);
}

// One routing iteration, NC n's per block processed as NC/2 pairs.
// Wave-parity n-split: lane (o = t&31, bl = t>>5); slot = bl&3, par = bl>>2.
// Thread owns b = b0 + slot + 4g (g=0..3). Waves with par==0 compute even n of
// each staged pair, par==1 the odd n -> only 8 waves read each 16KB W tile
// (half the DS traffic of NG=2), and one barrier per PAIR of n's.
// Partial sacc of the two parities are combined via an LDS epilogue.
// vcum == nullptr -> uniform c = 1/32 (iteration 1).
template<int NC>
__global__ __launch_bounds__(256, 2) void caps_route(
    const float* __restrict__ x,     // [B, N, DI]
    const float* __restrict__ w,     // [N, O, DO, DI]
    const float* __restrict__ vcum,  // [B, O, DO] or nullptr
    float* __restrict__ spart)       // [nch, B, O, DO]
{
    const int t    = threadIdx.x;
    const int o    = t & 31;
    const int bl   = t >> 5;          // 0..7
    const int slot = bl & 3;
    const int par  = bl >> 2;         // 0: even n, 1: odd n
    const int n0 = blockIdx.x * NC;
    const int b0 = blockIdx.y * BPB;

    // wbuf[pairbuf][subn]: phys float4 slot o*32 + (i2^o) holds w[n][o][i2]
    // (XOR bank swizzle -> conflict-free b128 reads; 2-way same-address
    // broadcast across the bl-pair of a half... free). Staging keeps LDS dest
    // lane-linear; GLOBAL index pre-swizzled (gq).
    __shared__ float4 wbuf[2][2][1024];   // 64 KB
    __shared__ float4 xbuf[NC][BPB][2];   // 4 KB at NC=8

    int gq[4];
#pragma unroll
    for (int k = 0; k < 4; ++k) {
        int p = k * 256 + t;
        gq[k] = (p & ~31) | ((p ^ (p >> 5)) & 31);
    }
    auto stageW = [&](int n, int c, int s2) {
        const float4* wg = (const float4*)(w + (size_t)n * (Oo * DOv * DIv));
#pragma unroll
        for (int k = 0; k < 4; ++k)
            gload_lds16(&wg[gq[k]], &wbuf[c][s2][k * 256 + t]);
    };

    // stage all NC x-tiles once (NC*BPB*2 = 256 float4 at NC=8)
    for (int q = t; q < NC * BPB * 2; q += 256) {
        int nn = q >> 5, bb = (q >> 1) & 15, h = q & 1;
        xbuf[nn][bb][h] = ((const float4*)(
            x + ((size_t)(b0 + bb) * Nn + (size_t)(n0 + nn)) * DIv))[h];
    }

    const bool have_v = (vcum != nullptr);
    float vc[NG][DOv];
    if (have_v) {
#pragma unroll
        for (int g = 0; g < NG; ++g) {
            const float4* vp = (const float4*)(
                vcum + ((size_t)(b0 + slot + 4 * g) * Oo + o) * DOv);
#pragma unroll
            for (int q = 0; q < 4; ++q) {
                float4 v = vp[q];
                vc[g][4*q+0] = v.x; vc[g][4*q+1] = v.y;
                vc[g][4*q+2] = v.z; vc[g][4*q+3] = v.w;
            }
        }
    }

    float sacc[NG][DOv];
#pragma unroll
    for (int g = 0; g < NG; ++g)
#pragma unroll
        for (int i = 0; i < DOv; ++i) sacc[g][i] = 0.f;

    stageW(n0 + 0, 0, 0);
    stageW(n0 + 1, 0, 1);

    constexpr int NP = NC / 2;
#pragma unroll
    for (int p = 0; p < NP; ++p) {
        __syncthreads();   // implicit vmcnt(0): pair p staged; xbuf visible
        if (p + 1 < NP) {  // prefetch next pair under this pair's compute;
                           // target buf's reads finished at iter p-1 (race-free)
            stageW(n0 + 2 * p + 2, (p + 1) & 1, 0);
            stageW(n0 + 2 * p + 3, (p + 1) & 1, 1);
        }

        const int nn = 2 * p + par;        // this wave's n within the chunk

        // x rows for this thread's 4 b's (broadcast within half-wave)
        float xa[NG][DIv];
#pragma unroll
        for (int g = 0; g < NG; ++g) {
            float4 a = xbuf[nn][slot + 4 * g][0];
            float4 b = xbuf[nn][slot + 4 * g][1];
            xa[g][0] = a.x; xa[g][1] = a.y; xa[g][2] = a.z; xa[g][3] = a.w;
            xa[g][4] = b.x; xa[g][5] = b.y; xa[g][6] = b.z; xa[g][7] = b.w;
        }

        float xh[NG][DOv];
#pragma unroll
        for (int g = 0; g < NG; ++g)
#pragma unroll
            for (int i = 0; i < DOv; ++i) xh[g][i] = 0.f;
#pragma unroll
        for (int i2 = 0; i2 < 32; ++i2) {
            float4 wv = wbuf[p & 1][par][o * 32 + (i2 ^ o)];  // w[n][o][i2*4..+3]
            const int i = i2 >> 1, jb = (i2 & 1) * 4;
#pragma unroll
            for (int g = 0; g < NG; ++g) {
                float acc = xh[g][i];
                acc = fmaf(wv.x, xa[g][jb + 0], acc);
                acc = fmaf(wv.y, xa[g][jb + 1], acc);
                acc = fmaf(wv.z, xa[g][jb + 2], acc);
                acc = fmaf(wv.w, xa[g][jb + 3], acc);
                xh[g][i] = acc;
            }
        }

        float c[NG];
        if (have_v) {
            float e[NG];
#pragma unroll
            for (int g = 0; g < NG; ++g) {
                float l = 0.f;
#pragma unroll
                for (int i = 0; i < DOv; ++i) l += xh[g][i] * vc[g][i];
                e[g] = __expf(l);            // |l| < 1: no max-sub needed
            }
            float r[NG];
#pragma unroll
            for (int g = 0; g < NG; ++g) r[g] = e[g];
#pragma unroll
            for (int d = 16; d >= 1; d >>= 1)   // stays within the 32-lane half
#pragma unroll
                for (int g = 0; g < NG; ++g) r[g] += __shfl_xor(r[g], d);
#pragma unroll
            for (int g = 0; g < NG; ++g) c[g] = e[g] / r[g];
        } else {
#pragma unroll
            for (int g = 0; g < NG; ++g) c[g] = 1.0f / 32.0f;
        }

#pragma unroll
        for (int g = 0; g < NG; ++g)
#pragma unroll
            for (int i = 0; i < DOv; ++i) sacc[g][i] += c[g] * xh[g][i];
    }

    // Epilogue: combine even/odd parity partials via LDS (reuse wbuf as scratch:
    // 128 threads x 16 float4 = 32 KB), then par==0 threads store to spart.
    __syncthreads();                       // all compute reads of wbuf done
    float4* scr = &wbuf[0][0][0];
    const int tl = o + 32 * slot;          // 0..127, same for the two parities
    if (par == 1) {
#pragma unroll
        for (int k = 0; k < 16; ++k) {     // k = g*4 + q, rotated to dodge banks
            int g = k >> 2, q = k & 3;
            scr[tl * 16 + ((k + tl) & 15)] =
                make_float4(sacc[g][4*q], sacc[g][4*q+1], sacc[g][4*q+2], sacc[g][4*q+3]);
        }
    }
    __syncthreads();
    if (par == 0) {
        float* pp = spart + (size_t)blockIdx.x * (Bb * Oo * DOv);
#pragma unroll
        for (int k = 0; k < 16; ++k) {
            int g = k >> 2, q = k & 3;
            float4 v = scr[tl * 16 + ((k + tl) & 15)];
            float4 r = make_float4(sacc[g][4*q] + v.x, sacc[g][4*q+1] + v.y,
                                   sacc[g][4*q+2] + v.z, sacc[g][4*q+3] + v.w);
            ((float4*)(pp + ((size_t)(b0 + slot + 4*g) * Oo + o) * DOv))[q] = r;
        }
    }
}

// Reduce nch partials + squash. One wave per (b, o); float4 lanes: q = t&3, pg = t>>2.
__global__ __launch_bounds__(64) void caps_squash(
    const float* __restrict__ spart, int nch,
    const float* __restrict__ vin,   // may be nullptr (treated as 0)
    float* __restrict__ vout,        // may be nullptr
    float* __restrict__ out)         // may be nullptr
{
    const int b = blockIdx.x, oo = blockIdx.y;
    const int t = threadIdx.x;
    const int q = t & 3, pg = t >> 2;          // 16 p-groups
    const size_t base4 = ((size_t)b * Oo + oo) * (DOv / 4) + q;
    const float4* sp4 = (const float4*)spart;
    const size_t chunk4 = (size_t)Bb * Oo * DOv / 4;

    float4 s = make_float4(0.f, 0.f, 0.f, 0.f);
    for (int p = pg; p < nch; p += 16) {
        float4 v = sp4[(size_t)p * chunk4 + base4];
        s.x += v.x; s.y += v.y; s.z += v.z; s.w += v.w;
    }
#pragma unroll
    for (int d = 4; d <= 32; d <<= 1) {
        s.x += __shfl_xor(s.x, d); s.y += __shfl_xor(s.y, d);
        s.z += __shfl_xor(s.z, d); s.w += __shfl_xor(s.w, d);
    }
    float n2 = s.x * s.x + s.y * s.y + s.z * s.z + s.w * s.w;
    n2 += __shfl_xor(n2, 1);
    n2 += __shfl_xor(n2, 2);
    float sc = n2 / ((1.f + n2) * sqrtf(n2 + 1e-7f));
    if (t < 4) {
        float4 vj = make_float4(s.x * sc, s.y * sc, s.z * sc, s.w * sc);
        size_t i4 = base4;
        if (vout) {
            float4 vi = vin ? ((const float4*)vin)[i4] : make_float4(0.f, 0.f, 0.f, 0.f);
            ((float4*)vout)[i4] = make_float4(vi.x + vj.x, vi.y + vj.y, vi.z + vj.z, vi.w + vj.w);
        }
        if (out) ((float4*)out)[i4] = vj;
    }
}

extern "C" void kernel_launch(void* const* d_in, const int* in_sizes, int n_in,
                              void* d_out, int out_size, void* d_ws, size_t ws_size,
                              hipStream_t stream)
{
    const float* x = (const float*)d_in[0];
    const float* w = (const float*)d_in[1];
    float* out = (float*)d_out;

    // nch=144, NC=8 -> grid (144,4) = 576 blocks (2.25/CU at 2 waves/SIMD),
    // spart 18.9 MB (proven-cheap squash).
    int nch = 144;
    size_t need = ((size_t)nch * Bb * Oo * DOv + (size_t)Bb * Oo * DOv) * sizeof(float);
    if (need > ws_size) nch = 16;    // fallback for tiny ws (NC=72)

    float* spart = (float*)d_ws;
    float* vcum  = spart + (size_t)nch * Bb * Oo * DOv;

    dim3 blk(256);
    dim3 sgrid(Bb, Oo), sblk(64);
    dim3 grid(nch, Bb / BPB);

    if (nch == 144) {
        caps_route<8><<<grid, blk, 0, stream>>>(x, w, nullptr, spart);
        caps_squash<<<sgrid, sblk, 0, stream>>>(spart, nch, nullptr, vcum, nullptr);
        caps_route<8><<<grid, blk, 0, stream>>>(x, w, vcum, spart);
        caps_squash<<<sgrid, sblk, 0, stream>>>(spart, nch, vcum, vcum, nullptr);
        caps_route<8><<<grid, blk, 0, stream>>>(x, w, vcum, spart);
        caps_squash<<<sgrid, sblk, 0, stream>>>(spart, nch, nullptr, nullptr, out);
    } else {
        caps_route<72><<<grid, blk, 0, stream>>>(x, w, nullptr, spart);
        caps_squash<<<sgrid, sblk, 0, stream>>>(spart, nch, nullptr, vcum, nullptr);
        caps_route<72><<<grid, blk, 0, stream>>>(x, w, vcum, spart);
        caps_squash<<<sgrid, sblk, 0, stream>>>(spart, nch, vcum, vcum, nullptr);
        caps_route<72><<<grid, blk, 0, stream>>>(x, w, vcum, spart);
        caps_squash<<<sgrid, sblk, 0, stream>>>(spart, nch, nullptr, nullptr, out);
    }
}

// Round 11
// 113.287 us; speedup vs baseline: 2.1234x; 2.1234x over previous
//
#include <hip/hip_runtime.h>

#define Bb 64
#define Nn 1152
#define Oo 32
#define DOv 16
#define DIv 8
#define BPB 16   // b's per block: 4 waves x NG b's
#define NG 4     // b's per thread (wave-uniform b set)

// async global->LDS, 16B per lane
__device__ __forceinline__ void gload_lds16(const void* g, void* l) {
    __builtin_amdgcn_global_load_lds(
        (const __attribute__((address_space(1))) unsigned*)g,
        (__attribute__((address_space(3))) unsigned*)l, 16, 0, 0);
}

// One routing iteration, NC n's per block, ih-split register layout:
// lane = (o = t&31, ih = (t>>5)&1), wave wv = t>>6 owns b = b0 + wv*4 + g.
// Each thread accumulates only its i-half (i = ih*8 + 0..7) -> 32-float
// arrays, ~150 VGPR, 3 waves/SIMD. Per wave per n: 16 swizzled ds_read_b128
// (half the W traffic of the NG=2 structure). Proven R3 staging skeleton:
// xbuf upfront, wbuf double-buffered, stage-after-__syncthreads.
// vcum == nullptr -> uniform c = 1/32 (iteration 1).
template<int NC>
__global__ __launch_bounds__(256) void caps_route(
    const float* __restrict__ x,     // [B, N, DI]
    const float* __restrict__ w,     // [N, O, DO, DI]
    const float* __restrict__ vcum,  // [B, O, DO] or nullptr
    float* __restrict__ spart)       // [nch, B, O, DO]
{
    const int t  = threadIdx.x;
    const int o  = t & 31;
    const int ih = (t >> 5) & 1;
    const int wv = t >> 6;            // 0..3
    const int n0 = blockIdx.x * NC;
    const int b0 = blockIdx.y * BPB;
    const int bw = b0 + wv * NG;      // this wave's first b (wave-uniform)

    // wbuf phys float4 slot o*32 + (i2^o) holds logical w[n][o][i2] (XOR bank
    // swizzle -> conflict-free b128 reads). LDS dest of global_load_lds stays
    // lane-linear; the GLOBAL index is pre-swizzled (gq).
    __shared__ float4 wbuf[2][1024];      // 32 KB, double-buffered
    __shared__ float4 xbuf[NC][BPB][2];   // 6 KB at NC=6

    int gq[4];
#pragma unroll
    for (int k = 0; k < 4; ++k) {
        int p = k * 256 + t;
        gq[k] = (p & ~31) | ((p ^ (p >> 5)) & 31);
    }
    auto stageW = [&](int n, int c) {
        const float4* wg = (const float4*)(w + (size_t)n * (Oo * DOv * DIv));
#pragma unroll
        for (int k = 0; k < 4; ++k)
            gload_lds16(&wg[gq[k]], &wbuf[c][k * 256 + t]);
    };

    // stage all NC x-tiles once (NC*BPB*2 float4; <=256 at NC<=8)
    for (int q = t; q < NC * BPB * 2; q += 256) {
        int nn = q >> 5, bb = (q >> 1) & 15, h = q & 1;
        xbuf[nn][bb][h] = ((const float4*)(
            x + ((size_t)(b0 + bb) * Nn + (size_t)(n0 + nn)) * DIv))[h];
    }

    const bool have_v = (vcum != nullptr);
    float vc[NG][8];    // this thread's i-half of vcum for its 4 b's
    if (have_v) {
#pragma unroll
        for (int g = 0; g < NG; ++g) {
            const float4* vp = (const float4*)(
                vcum + (((size_t)(bw + g) * Oo + o) * DOv + ih * 8));
            float4 a = vp[0], bvec = vp[1];
            vc[g][0] = a.x;    vc[g][1] = a.y;    vc[g][2] = a.z;    vc[g][3] = a.w;
            vc[g][4] = bvec.x; vc[g][5] = bvec.y; vc[g][6] = bvec.z; vc[g][7] = bvec.w;
        }
    }

    float sacc[NG][8];
#pragma unroll
    for (int g = 0; g < NG; ++g)
#pragma unroll
        for (int i = 0; i < 8; ++i) sacc[g][i] = 0.f;

    stageW(n0, 0);
    int cur = 0;

#pragma unroll
    for (int nn = 0; nn < NC; ++nn) {
        __syncthreads();                     // wbuf[cur] ready (vmcnt drained); xbuf visible
        if (nn + 1 < NC) stageW(n0 + nn + 1, cur ^ 1);  // fly under compute

        // x rows for this wave's 4 b's (wave-uniform -> broadcast LDS reads)
        float xa[NG][DIv];
#pragma unroll
        for (int g = 0; g < NG; ++g) {
            float4 a = xbuf[nn][wv * NG + g][0];
            float4 bvec = xbuf[nn][wv * NG + g][1];
            xa[g][0] = a.x;    xa[g][1] = a.y;    xa[g][2] = a.z;    xa[g][3] = a.w;
            xa[g][4] = bvec.x; xa[g][5] = bvec.y; xa[g][6] = bvec.z; xa[g][7] = bvec.w;
        }

        // xh[g][ii], global i = ih*8 + ii ; 16 swizzled b128 reads (this half's i2)
        float xh[NG][8];
#pragma unroll
        for (int g = 0; g < NG; ++g)
#pragma unroll
            for (int i = 0; i < 8; ++i) xh[g][i] = 0.f;
#pragma unroll
        for (int k = 0; k < 16; ++k) {
            const int i2 = ih * 16 + k;
            float4 wv4 = wbuf[cur][o * 32 + ((i2 ^ o) & 31)];  // w[n][o][i2*4..+3]
            const int ii = k >> 1, jb = (k & 1) * 4;
#pragma unroll
            for (int g = 0; g < NG; ++g) {
                float acc = xh[g][ii];
                acc = fmaf(wv4.x, xa[g][jb + 0], acc);
                acc = fmaf(wv4.y, xa[g][jb + 1], acc);
                acc = fmaf(wv4.z, xa[g][jb + 2], acc);
                acc = fmaf(wv4.w, xa[g][jb + 3], acc);
                xh[g][ii] = acc;
            }
        }

        float c[NG];
        if (have_v) {
            float e[NG];
#pragma unroll
            for (int g = 0; g < NG; ++g) {
                float lp = 0.f;
#pragma unroll
                for (int i = 0; i < 8; ++i) lp += xh[g][i] * vc[g][i];
                float l = lp + __shfl_xor(lp, 32);   // combine i-halves
                e[g] = __expf(l);                    // |l| < 1: no max-sub
            }
            // denominator: each half reduces 2 g's over its 32 o-lanes, then swap
            float r0 = ih ? e[2] : e[0];
            float r1 = ih ? e[3] : e[1];
#pragma unroll
            for (int d = 16; d >= 1; d >>= 1) {      // stays within each 32-group
                r0 += __shfl_xor(r0, d);
                r1 += __shfl_xor(r1, d);
            }
            float s0 = __shfl_xor(r0, 32);           // other half's pair
            float s1 = __shfl_xor(r1, 32);
            float den0 = ih ? s0 : r0, den1 = ih ? s1 : r1;
            float den2 = ih ? r0 : s0, den3 = ih ? r1 : s1;
            c[0] = e[0] * __builtin_amdgcn_rcpf(den0);
            c[1] = e[1] * __builtin_amdgcn_rcpf(den1);
            c[2] = e[2] * __builtin_amdgcn_rcpf(den2);
            c[3] = e[3] * __builtin_amdgcn_rcpf(den3);
        } else {
#pragma unroll
            for (int g = 0; g < NG; ++g) c[g] = 1.0f / 32.0f;
        }

#pragma unroll
        for (int g = 0; g < NG; ++g)
#pragma unroll
            for (int i = 0; i < 8; ++i) sacc[g][i] += c[g] * xh[g][i];
        cur ^= 1;
    }

    // plain float4 stores; each (b,o,i) owned by exactly one thread
    float* p = spart + (size_t)blockIdx.x * (Bb * Oo * DOv);
#pragma unroll
    for (int g = 0; g < NG; ++g) {
        float* pg = p + (((size_t)(bw + g) * Oo + o) * DOv + ih * 8);
        ((float4*)pg)[0] = make_float4(sacc[g][0], sacc[g][1], sacc[g][2], sacc[g][3]);
        ((float4*)pg)[1] = make_float4(sacc[g][4], sacc[g][5], sacc[g][6], sacc[g][7]);
    }
}

// Reduce nch partials + squash. One wave per (b, o); float4 lanes: q = t&3, pg = t>>2.
__global__ __launch_bounds__(64) void caps_squash(
    const float* __restrict__ spart, int nch,
    const float* __restrict__ vin,   // may be nullptr (treated as 0)
    float* __restrict__ vout,        // may be nullptr
    float* __restrict__ out)         // may be nullptr
{
    const int b = blockIdx.x, oo = blockIdx.y;
    const int t = threadIdx.x;
    const int q = t & 3, pg = t >> 2;          // 16 p-groups
    const size_t base4 = ((size_t)b * Oo + oo) * (DOv / 4) + q;
    const float4* sp4 = (const float4*)spart;
    const size_t chunk4 = (size_t)Bb * Oo * DOv / 4;

    float4 s = make_float4(0.f, 0.f, 0.f, 0.f);
    for (int p = pg; p < nch; p += 16) {
        float4 v = sp4[(size_t)p * chunk4 + base4];
        s.x += v.x; s.y += v.y; s.z += v.z; s.w += v.w;
    }
#pragma unroll
    for (int d = 4; d <= 32; d <<= 1) {
        s.x += __shfl_xor(s.x, d); s.y += __shfl_xor(s.y, d);
        s.z += __shfl_xor(s.z, d); s.w += __shfl_xor(s.w, d);
    }
    float n2 = s.x * s.x + s.y * s.y + s.z * s.z + s.w * s.w;
    n2 += __shfl_xor(n2, 1);
    n2 += __shfl_xor(n2, 2);
    float sc = n2 / ((1.f + n2) * sqrtf(n2 + 1e-7f));
    if (t < 4) {
        float4 vj = make_float4(s.x * sc, s.y * sc, s.z * sc, s.w * sc);
        size_t i4 = base4;
        if (vout) {
            float4 vi = vin ? ((const float4*)vin)[i4] : make_float4(0.f, 0.f, 0.f, 0.f);
            ((float4*)vout)[i4] = make_float4(vi.x + vj.x, vi.y + vj.y, vi.z + vj.z, vi.w + vj.w);
        }
        if (out) ((float4*)out)[i4] = vj;
    }
}

extern "C" void kernel_launch(void* const* d_in, const int* in_sizes, int n_in,
                              void* d_out, int out_size, void* d_ws, size_t ws_size,
                              hipStream_t stream)
{
    const float* x = (const float*)d_in[0];
    const float* w = (const float*)d_in[1];
    float* out = (float*)d_out;

    // nch=192/NC=6 -> 768 blocks (~3/CU at 3 waves/SIMD), spart 25.2 MB.
    // Fallback nch=144/NC=8 (proven to fit), then 16/72.
    auto need = [](int nch) {
        return ((size_t)nch * Bb * Oo * DOv + (size_t)Bb * Oo * DOv) * sizeof(float);
    };
    int nch = 192;
    if (need(nch) > ws_size) nch = 144;
    if (need(nch) > ws_size) nch = 16;

    float* spart = (float*)d_ws;
    float* vcum  = spart + (size_t)nch * Bb * Oo * DOv;

    dim3 blk(256);
    dim3 sgrid(Bb, Oo), sblk(64);
    dim3 grid(nch, Bb / BPB);

    if (nch == 192) {
        caps_route<6><<<grid, blk, 0, stream>>>(x, w, nullptr, spart);
        caps_squash<<<sgrid, sblk, 0, stream>>>(spart, nch, nullptr, vcum, nullptr);
        caps_route<6><<<grid, blk, 0, stream>>>(x, w, vcum, spart);
        caps_squash<<<sgrid, sblk, 0, stream>>>(spart, nch, vcum, vcum, nullptr);
        caps_route<6><<<grid, blk, 0, stream>>>(x, w, vcum, spart);
        caps_squash<<<sgrid, sblk, 0, stream>>>(spart, nch, nullptr, nullptr, out);
    } else if (nch == 144) {
        caps_route<8><<<grid, blk, 0, stream>>>(x, w, nullptr, spart);
        caps_squash<<<sgrid, sblk, 0, stream>>>(spart, nch, nullptr, vcum, nullptr);
        caps_route<8><<<grid, blk, 0, stream>>>(x, w, vcum, spart);
        caps_squash<<<sgrid, sblk, 0, stream>>>(spart, nch, vcum, vcum, nullptr);
        caps_route<8><<<grid, blk, 0, stream>>>(x, w, vcum, spart);
        caps_squash<<<sgrid, sblk, 0, stream>>>(spart, nch, nullptr, nullptr, out);
    } else {
        caps_route<72><<<grid, blk, 0, stream>>>(x, w, nullptr, spart);
        caps_squash<<<sgrid, sblk, 0, stream>>>(spart, nch, nullptr, vcum, nullptr);
        caps_route<72><<<grid, blk, 0, stream>>>(x, w, vcum, spart);
        caps_squash<<<sgrid, sblk, 0, stream>>>(spart, nch, vcum, vcum, nullptr);
        caps_route<72><<<grid, blk, 0, stream>>>(x, w, vcum, spart);
        caps_squash<<<sgrid, sblk, 0, stream>>>(spart, nch, nullptr, nullptr, out);
    }
}